// Round 1
// baseline (715.617 us; speedup 1.0000x reference)
//
#include <hip/hip_runtime.h>
#include <hip/hip_bf16.h>

typedef __hip_bfloat16 bf16;
typedef __bf16 bf16x8 __attribute__((ext_vector_type(8)));
typedef float f32x4 __attribute__((ext_vector_type(4)));

#define S_LEN 2048
#define BATCH 2
#define HID 1024
#define NHEAD 16
#define DH 64
#define ROWS (S_LEN * BATCH)        // 4096
#define HEADS_TOT (BATCH * NHEAD)   // 32
#define CTX_ELEMS (S_LEN * BATCH * HID)  // 4194304

// ---------------- prep: fp32 -> bf16 conversions ----------------

__global__ __launch_bounds__(256) void cvt_x_kernel(const float* __restrict__ x, bf16* __restrict__ xb) {
    int i = (blockIdx.x * 256 + threadIdx.x) * 4;
    float4 v = *(const float4*)(x + i);
    bf16 tmp[4] = {__float2bfloat16(v.x), __float2bfloat16(v.y),
                   __float2bfloat16(v.z), __float2bfloat16(v.w)};
    *(uint2*)(xb + i) = *(uint2*)tmp;
}

// Wat[192][1024]: Wat[p*64+n][k] = w{p}a[k][n]  (transposed, bf16)
__global__ __launch_bounds__(256) void prep_wat_kernel(const float* __restrict__ wqa, const float* __restrict__ wka,
                                                       const float* __restrict__ wva, bf16* __restrict__ Wat) {
    int o = blockIdx.x * 256 + threadIdx.x;  // 192*1024 total
    int nrow = o >> 10, k = o & 1023;
    int pj = nrow >> 6, nl = nrow & 63;
    const float* w = pj == 0 ? wqa : (pj == 1 ? wka : wva);
    Wat[o] = __float2bfloat16(w[k * 64 + nl]);
}

// Wbt[3][1024][64]: Wbt[p][n][k] = w{p}b[k][n]
__global__ __launch_bounds__(256) void prep_wbt_kernel(const float* __restrict__ wqb, const float* __restrict__ wkb,
                                                       const float* __restrict__ wvb, bf16* __restrict__ Wbt) {
    int o = blockIdx.x * 256 + threadIdx.x;  // 3*65536 total
    int pj = o >> 16; int rem = o & 65535; int n = rem >> 6; int k = rem & 63;
    const float* w = pj == 0 ? wqb : (pj == 1 ? wkb : wvb);
    Wbt[o] = __float2bfloat16(w[k * 1024 + n]);
}

// ---------------- stage A: T[4096][192] = x @ [Wqa|Wka|Wva] + bias ----------------

__global__ __launch_bounds__(256) void stage_a_kernel(const bf16* __restrict__ xb, const bf16* __restrict__ Wat,
                                                      const float* __restrict__ bqa, const float* __restrict__ bka,
                                                      const float* __restrict__ bva, bf16* __restrict__ T) {
    __shared__ __align__(16) bf16 Al[64][72];
    __shared__ __align__(16) bf16 Bl[192][72];
    int tid = threadIdx.x;
    int wave = tid >> 6, lane = tid & 63, quad = lane >> 4, l16 = lane & 15;
    int blk = blockIdx.x;
    f32x4 acc[12];
#pragma unroll
    for (int n = 0; n < 12; n++) acc[n] = (f32x4){0.f, 0.f, 0.f, 0.f};
    for (int k0 = 0; k0 < 1024; k0 += 64) {
        __syncthreads();
#pragma unroll
        for (int i = 0; i < 2; i++) {
            int e = tid + i * 256; int r = e >> 3, c = (e & 7) * 8;
            *(uint4*)&Al[r][c] = *(const uint4*)&xb[(size_t)(blk * 64 + r) * 1024 + k0 + c];
        }
#pragma unroll
        for (int i = 0; i < 6; i++) {
            int e = tid + i * 256; int r = e >> 3, c = (e & 7) * 8;
            *(uint4*)&Bl[r][c] = *(const uint4*)&Wat[(size_t)r * 1024 + k0 + c];
        }
        __syncthreads();
#pragma unroll
        for (int kk = 0; kk < 64; kk += 32) {
            bf16x8 a = *(const bf16x8*)&Al[wave * 16 + l16][kk + quad * 8];
#pragma unroll
            for (int n = 0; n < 12; n++) {
                bf16x8 b = *(const bf16x8*)&Bl[n * 16 + l16][kk + quad * 8];
                acc[n] = __builtin_amdgcn_mfma_f32_16x16x32_bf16(a, b, acc[n], 0, 0, 0);
            }
        }
    }
#pragma unroll
    for (int n = 0; n < 12; n++) {
        int col = n * 16 + l16;
        int pj = col >> 6, cl = col & 63;
        float bias = pj == 0 ? bqa[cl] : (pj == 1 ? bka[cl] : bva[cl]);
#pragma unroll
        for (int reg = 0; reg < 4; reg++) {
            int r = blk * 64 + wave * 16 + quad * 4 + reg;
            T[(size_t)r * 192 + col] = __float2bfloat16(acc[n][reg] + bias);
        }
    }
}

// ---------------- stage B: Q/K -> [head][s][64], V -> [head][64][s] ----------------

__global__ __launch_bounds__(256) void stage_b_kernel(const bf16* __restrict__ T, const bf16* __restrict__ Wbt,
                                                      const float* __restrict__ bqb, const float* __restrict__ bkb,
                                                      const float* __restrict__ bvb, bf16* __restrict__ Qh,
                                                      bf16* __restrict__ Kh, bf16* __restrict__ Vt) {
    __shared__ __align__(16) bf16 Al[64][72];
    int tid = threadIdx.x;
    int wave = tid >> 6, lane = tid & 63, quad = lane >> 4, l16 = lane & 15;
    int blk = blockIdx.x, pj = blockIdx.y;
#pragma unroll
    for (int i = 0; i < 2; i++) {
        int e = tid + i * 256; int r = e >> 3, c = (e & 7) * 8;
        *(uint4*)&Al[r][c] = *(const uint4*)&T[(size_t)(blk * 64 + r) * 192 + pj * 64 + c];
    }
    __syncthreads();
    const bf16* wbt = Wbt + (size_t)pj * 65536;
    const float* bb = pj == 0 ? bqb : (pj == 1 ? bkb : bvb);
    bf16x8 a0 = *(const bf16x8*)&Al[wave * 16 + l16][quad * 8];
    bf16x8 a1 = *(const bf16x8*)&Al[wave * 16 + l16][32 + quad * 8];
    for (int n = 0; n < 64; n++) {
        bf16x8 b0 = *(const bf16x8*)&wbt[(n * 16 + l16) * 64 + quad * 8];
        bf16x8 b1 = *(const bf16x8*)&wbt[(n * 16 + l16) * 64 + 32 + quad * 8];
        f32x4 acc = (f32x4){0.f, 0.f, 0.f, 0.f};
        acc = __builtin_amdgcn_mfma_f32_16x16x32_bf16(a0, b0, acc, 0, 0, 0);
        acc = __builtin_amdgcn_mfma_f32_16x16x32_bf16(a1, b1, acc, 0, 0, 0);
        int col = n * 16 + l16;
        int h = col >> 6, d = col & 63;
        float bias = bb[col];
#pragma unroll
        for (int reg = 0; reg < 4; reg++) {
            int r = blk * 64 + wave * 16 + quad * 4 + reg;
            int s = r >> 1, b = r & 1;
            int head = b * 16 + h;
            float v = acc[reg] + bias;
            if (pj == 0)      Qh[(size_t)(head * 2048 + s) * 64 + d] = __float2bfloat16(v);
            else if (pj == 1) Kh[(size_t)(head * 2048 + s) * 64 + d] = __float2bfloat16(v);
            else              Vt[(size_t)(head * 64 + d) * 2048 + s] = __float2bfloat16(v);
        }
    }
}

// ---------------- row squared-norms of Q and K ----------------

__global__ __launch_bounds__(256) void sqnorm_kernel(const bf16* __restrict__ Qh, const bf16* __restrict__ Kh,
                                                     float* __restrict__ qsq, float* __restrict__ ksq) {
    int tid = threadIdx.x;
    int sub = tid >> 4, l = tid & 15;
    int row = blockIdx.x * 16 + sub;  // 0..131071
    const bf16* src; float* dst; int r;
    if (row < 65536) { src = Qh; dst = qsq; r = row; }
    else             { src = Kh; dst = ksq; r = row - 65536; }
    const bf16* p = src + (size_t)r * 64 + l * 4;
    float s = 0.f;
#pragma unroll
    for (int j = 0; j < 4; j++) { float v = __bfloat162float(p[j]); s += v * v; }
#pragma unroll
    for (int off = 8; off >= 1; off >>= 1) s += __shfl_xor(s, off, 16);
    if (l == 0) dst[r] = s;
}

// ---------------- fused attention ----------------
// grid (32 qblks, 32 heads), 256 threads (4 waves x 16 q-rows).
// scores <= 0 always (negative scaled squared distance) so exp needs no max-trick.

__global__ __launch_bounds__(256) void attn_kernel(const bf16* __restrict__ Qh, const bf16* __restrict__ Kh,
                                                   const bf16* __restrict__ Vt, const float* __restrict__ qsq,
                                                   const float* __restrict__ ksq, float* __restrict__ out) {
    __shared__ __align__(16) bf16 Kl[64][72];
    __shared__ __align__(16) bf16 Vl[64][72];        // Vl[d][t]
    __shared__ __align__(16) bf16 Pl[4][16][72];     // per-wave P tile
    int tid = threadIdx.x;
    int wave = tid >> 6, lane = tid & 63, quad = lane >> 4, l16 = lane & 15;
    int qblk = blockIdx.x, head = blockIdx.y;
    const bf16* Qp = Qh + ((size_t)head * 2048 + qblk * 64) * 64;
    const bf16* Kp = Kh + (size_t)head * 2048 * 64;
    const bf16* Vp = Vt + (size_t)head * 64 * 2048;
    float* out_sc = out + (size_t)CTX_ELEMS + (size_t)head * 2048 * 2048;

    int m = wave * 16 + l16;
    bf16x8 qa0 = *(const bf16x8*)&Qp[m * 64 + quad * 8];
    bf16x8 qa1 = *(const bf16x8*)&Qp[m * 64 + 32 + quad * 8];
    float qs[4];
#pragma unroll
    for (int reg = 0; reg < 4; reg++)
        qs[reg] = qsq[head * 2048 + qblk * 64 + wave * 16 + quad * 4 + reg];
    f32x4 ctx[4];
#pragma unroll
    for (int n = 0; n < 4; n++) ctx[n] = (f32x4){0.f, 0.f, 0.f, 0.f};

    for (int t0 = 0; t0 < 2048; t0 += 64) {
        __syncthreads();
#pragma unroll
        for (int i = 0; i < 2; i++) {
            int e = tid + i * 256; int r = e >> 3, c = (e & 7) * 8;
            *(uint4*)&Kl[r][c] = *(const uint4*)&Kp[(size_t)(t0 + r) * 64 + c];
            *(uint4*)&Vl[r][c] = *(const uint4*)&Vp[(size_t)r * 2048 + t0 + c];
        }
        __syncthreads();
        int srow_base = qblk * 64 + wave * 16;
#pragma unroll
        for (int n = 0; n < 4; n++) {
            bf16x8 b0 = *(const bf16x8*)&Kl[n * 16 + l16][quad * 8];
            bf16x8 b1 = *(const bf16x8*)&Kl[n * 16 + l16][32 + quad * 8];
            f32x4 acc = (f32x4){0.f, 0.f, 0.f, 0.f};
            acc = __builtin_amdgcn_mfma_f32_16x16x32_bf16(qa0, b0, acc, 0, 0, 0);
            acc = __builtin_amdgcn_mfma_f32_16x16x32_bf16(qa1, b1, acc, 0, 0, 0);
            float kq = ksq[head * 2048 + t0 + n * 16 + l16];
#pragma unroll
            for (int reg = 0; reg < 4; reg++) {
                float sc = (qs[reg] + kq - 2.0f * acc[reg]) * -0.0625f;
                out_sc[(size_t)(srow_base + quad * 4 + reg) * 2048 + (t0 + n * 16 + l16)] = sc;
                Pl[wave][quad * 4 + reg][n * 16 + l16] = __float2bfloat16(__expf(sc));
            }
        }
        // P written and read by the SAME wave only: drain LDS, block reordering.
        __asm__ volatile("s_waitcnt lgkmcnt(0)" ::: "memory");
        bf16x8 pa0 = *(const bf16x8*)&Pl[wave][l16][quad * 8];
        bf16x8 pa1 = *(const bf16x8*)&Pl[wave][l16][32 + quad * 8];
#pragma unroll
        for (int n = 0; n < 4; n++) {
            bf16x8 vb0 = *(const bf16x8*)&Vl[n * 16 + l16][quad * 8];
            bf16x8 vb1 = *(const bf16x8*)&Vl[n * 16 + l16][32 + quad * 8];
            ctx[n] = __builtin_amdgcn_mfma_f32_16x16x32_bf16(pa0, vb0, ctx[n], 0, 0, 0);
            ctx[n] = __builtin_amdgcn_mfma_f32_16x16x32_bf16(pa1, vb1, ctx[n], 0, 0, 0);
        }
    }
    int b = head >> 4, h = head & 15;
#pragma unroll
    for (int n = 0; n < 4; n++) {
#pragma unroll
        for (int reg = 0; reg < 4; reg++) {
            int s = qblk * 64 + wave * 16 + quad * 4 + reg;
            int col = h * 64 + n * 16 + l16;
            out[(size_t)(s * 2 + b) * 1024 + col] = ctx[n][reg];
        }
    }
}

// ---------------- launcher ----------------

extern "C" void kernel_launch(void* const* d_in, const int* in_sizes, int n_in,
                              void* d_out, int out_size, void* d_ws, size_t ws_size,
                              hipStream_t stream) {
    const float* x   = (const float*)d_in[0];
    const float* wqa = (const float*)d_in[1];  const float* bqa = (const float*)d_in[2];
    const float* wqb = (const float*)d_in[3];  const float* bqb = (const float*)d_in[4];
    const float* wka = (const float*)d_in[5];  const float* bka = (const float*)d_in[6];
    const float* wkb = (const float*)d_in[7];  const float* bkb = (const float*)d_in[8];
    const float* wva = (const float*)d_in[9];  const float* bva = (const float*)d_in[10];
    const float* wvb = (const float*)d_in[11]; const float* bvb = (const float*)d_in[12];
    float* out = (float*)d_out;

    char* w = (char*)d_ws;
    bf16* xb  = (bf16*)w;  w += (size_t)ROWS * HID * 2;          // 8 MB
    bf16* Wat = (bf16*)w;  w += (size_t)192 * 1024 * 2;          // 384 KB
    bf16* Wbt = (bf16*)w;  w += (size_t)3 * 1024 * 64 * 2;       // 384 KB
    bf16* T   = (bf16*)w;  w += (size_t)ROWS * 192 * 2;          // 1.5 MB
    bf16* Qh  = (bf16*)w;  w += (size_t)HEADS_TOT * 2048 * 64 * 2;  // 8 MB
    bf16* Kh  = (bf16*)w;  w += (size_t)HEADS_TOT * 2048 * 64 * 2;  // 8 MB
    bf16* Vt  = (bf16*)w;  w += (size_t)HEADS_TOT * 64 * 2048 * 2;  // 8 MB
    float* qsq = (float*)w; w += (size_t)HEADS_TOT * 2048 * 4;   // 256 KB
    float* ksq = (float*)w; w += (size_t)HEADS_TOT * 2048 * 4;   // 256 KB

    cvt_x_kernel<<<4096, 256, 0, stream>>>(x, xb);
    prep_wat_kernel<<<768, 256, 0, stream>>>(wqa, wka, wva, Wat);
    prep_wbt_kernel<<<768, 256, 0, stream>>>(wqb, wkb, wvb, Wbt);
    stage_a_kernel<<<64, 256, 0, stream>>>(xb, Wat, bqa, bka, bva, T);
    stage_b_kernel<<<dim3(64, 3), 256, 0, stream>>>(T, Wbt, bqb, bkb, bvb, Qh, Kh, Vt);
    sqnorm_kernel<<<8192, 256, 0, stream>>>(Qh, Kh, qsq, ksq);
    attn_kernel<<<dim3(32, 32), 256, 0, stream>>>(Qh, Kh, Vt, qsq, ksq, out);
}